// Round 5
// baseline (184.326 us; speedup 1.0000x reference)
//
#include <hip/hip_runtime.h>
#include <hip/hip_bf16.h>
#include <math.h>

constexpr int B = 8, N = 2048, H = 512, A = 128;

typedef __bf16 bf16x8 __attribute__((ext_vector_type(8)));
typedef float f32x4 __attribute__((ext_vector_type(4)));
typedef unsigned short ushort_t;
typedef unsigned int uint_t;

__device__ __forceinline__ f32x4 mfma16(bf16x8 a, bf16x8 b, f32x4 c) {
    return __builtin_amdgcn_mfma_f32_16x16x32_bf16(a, b, c, 0, 0, 0);
}
__device__ __forceinline__ ushort_t f2bf(float v) {
    return __builtin_bit_cast(ushort_t, __float2bfloat16(v));
}
__device__ __forceinline__ float bf2f(ushort_t u) {
    return __bfloat162float(__builtin_bit_cast(__hip_bfloat16, u));
}

// ---------------- K0: transpose + hi/lo split the weights ----------------
__global__ __launch_bounds__(256) void k0_conv(
    const float* __restrict__ Wq, const float* __restrict__ Wk,
    ushort_t* __restrict__ WqTh, ushort_t* __restrict__ WqTl,
    ushort_t* __restrict__ WkTh, ushort_t* __restrict__ WkTl)
{
    const int id = blockIdx.x * 256 + threadIdx.x;   // 65536 = 512*128
    const int k = id >> 7, n = id & 127;
    const float vq = Wq[id];
    const ushort_t qh = f2bf(vq);
    const ushort_t ql = f2bf(vq - bf2f(qh));
    WqTh[n * 512 + k] = qh; WqTl[n * 512 + k] = ql;
    const float vk = Wk[id];
    const ushort_t kh = f2bf(vk);
    const ushort_t kl = f2bf(vk - bf2f(kh));
    WkTh[n * 512 + k] = kh; WkTl[n * 512 + k] = kl;
}

// ---------------- K1: MFMA projections + gate; stores hi/lo planes ----------------
__global__ __launch_bounds__(256) void k1_mfma(
    const float* __restrict__ x,
    const ushort_t* __restrict__ WqTh, const ushort_t* __restrict__ WqTl,
    const ushort_t* __restrict__ WkTh, const ushort_t* __restrict__ WkTl,
    const float* __restrict__ bq, const float* __restrict__ bk,
    const float* __restrict__ Wv, const float* __restrict__ bv,
    ushort_t* __restrict__ Qhi, ushort_t* __restrict__ Qlo,
    ushort_t* __restrict__ Khi, ushort_t* __restrict__ Klo, float* __restrict__ gb)
{
    __shared__ ushort_t xh[64 * 256], xl[64 * 256];   // 64 KiB
    __shared__ float gred[2][64];
    const int t = threadIdx.x;
    const int lane = t & 63, w = t >> 6;
    const int l15 = lane & 15, l4 = lane >> 4;
    const int m0 = blockIdx.x * 64;

    f32x4 acc[4][4];
    #pragma unroll
    for (int r = 0; r < 4; ++r)
        #pragma unroll
        for (int c = 0; c < 4; ++c) acc[r][c] = {0.f, 0.f, 0.f, 0.f};

    const ushort_t* WTh = (w < 2) ? WqTh : WkTh;
    const ushort_t* WTl = (w < 2) ? WqTl : WkTl;
    const int colbase = (w & 1) * 64;

    for (int ck = 0; ck < 2; ++ck) {
        __syncthreads();
        #pragma unroll
        for (int it = 0; it < 16; ++it) {
            const int idx = it * 256 + t;
            const int row = idx >> 6, c4 = idx & 63;
            const float4 v = *(const float4*)(x + (size_t)(m0 + row) * H + ck * 256 + c4 * 4);
            const ushort_t h0 = f2bf(v.x), h1 = f2bf(v.y), h2 = f2bf(v.z), h3 = f2bf(v.w);
            const ushort_t e0 = f2bf(v.x - bf2f(h0)), e1 = f2bf(v.y - bf2f(h1));
            const ushort_t e2 = f2bf(v.z - bf2f(h2)), e3 = f2bf(v.w - bf2f(h3));
            uint2 hh, ll;
            hh.x = (uint_t)h0 | ((uint_t)h1 << 16); hh.y = (uint_t)h2 | ((uint_t)h3 << 16);
            ll.x = (uint_t)e0 | ((uint_t)e1 << 16); ll.y = (uint_t)e2 | ((uint_t)e3 << 16);
            const int base = row * 512 + ((((c4 >> 1) << 4)) ^ ((row & 7) << 4)) + (c4 & 1) * 8;
            *(uint2*)((char*)xh + base) = hh;
            *(uint2*)((char*)xl + base) = ll;
        }
        __syncthreads();

        #pragma unroll
        for (int ks = 0; ks < 8; ++ks) {
            bf16x8 ah[4], al[4], bh[4], bl[4];
            const int kb = ks * 64 + l4 * 16;
            #pragma unroll
            for (int rb = 0; rb < 4; ++rb) {
                const int row = rb * 16 + l15;
                const int off = row * 512 + (kb ^ ((row & 7) << 4));
                ah[rb] = *(const bf16x8*)((const char*)xh + off);
                al[rb] = *(const bf16x8*)((const char*)xl + off);
            }
            const int kg = ck * 256 + ks * 32 + l4 * 8;
            #pragma unroll
            for (int cb = 0; cb < 4; ++cb) {
                const size_t woff = (size_t)(colbase + cb * 16 + l15) * 512 + kg;
                bh[cb] = *(const bf16x8*)(WTh + woff);
                bl[cb] = *(const bf16x8*)(WTl + woff);
            }
            #pragma unroll
            for (int rb = 0; rb < 4; ++rb)
                #pragma unroll
                for (int cb = 0; cb < 4; ++cb) {
                    acc[rb][cb] = mfma16(ah[rb], bh[cb], acc[rb][cb]);
                    acc[rb][cb] = mfma16(ah[rb], bl[cb], acc[rb][cb]);
                    acc[rb][cb] = mfma16(al[rb], bh[cb], acc[rb][cb]);
                }
        }
    }

    const float* bias = (w < 2) ? bq : bk;
    float bb[4], wv[4];
    #pragma unroll
    for (int cb = 0; cb < 4; ++cb) {
        bb[cb] = bias[colbase + cb * 16 + l15];
        wv[cb] = Wv[colbase + cb * 16 + l15];
    }
    float p[4][4];
    #pragma unroll
    for (int rb = 0; rb < 4; ++rb)
        #pragma unroll
        for (int g = 0; g < 4; ++g) {
            float ps = 0.f;
            #pragma unroll
            for (int cb = 0; cb < 4; ++cb) {
                const float v = acc[rb][cb][g] + bb[cb];
                acc[rb][cb][g] = v;
                ps = fmaf(v, wv[cb], ps);
            }
            p[rb][g] = ps;
        }

    ushort_t* OH = (w < 2) ? Qhi : Khi;
    ushort_t* OL = (w < 2) ? Qlo : Klo;
    #pragma unroll
    for (int rb = 0; rb < 4; ++rb) {
        const int row = m0 + rb * 16 + l4 * 4;
        #pragma unroll
        for (int cb = 0; cb < 4; ++cb) {
            const int col = colbase + cb * 16 + l15;
            #pragma unroll
            for (int g = 0; g < 4; ++g) {
                const float v = acc[rb][cb][g];
                const ushort_t hi = f2bf(v);
                const ushort_t lo = f2bf(v - bf2f(hi));
                OH[(size_t)(row + g) * A + col] = hi;
                OL[(size_t)(row + g) * A + col] = lo;
            }
        }
    }

    if (w < 2) {
        #pragma unroll
        for (int rb = 0; rb < 4; ++rb)
            #pragma unroll
            for (int g = 0; g < 4; ++g) {
                float v = p[rb][g];
                v += __shfl_xor(v, 1); v += __shfl_xor(v, 2);
                v += __shfl_xor(v, 4); v += __shfl_xor(v, 8);
                if (l15 == 0) gred[w][rb * 16 + l4 * 4 + g] = v;
            }
    }
    __syncthreads();
    if (t < 64) {
        const float z = gred[0][t] + gred[1][t] + bv[0];
        gb[m0 + t] = 1.f / (1.f + __expf(-z));
    }
}

// ---------------- K2: fused scores -> exp -> rowsum -> normalize -> out ----------------
// 512 WGs x 512 threads (8 waves). WG owns (batch b = bid&7, 32-row i-block).
// e-tile kept in LDS (32x2048 bf16 = 128 KB); K fragments streamed from L2.
__global__ __launch_bounds__(512) void k2_fused(
    const ushort_t* __restrict__ Qhi, const ushort_t* __restrict__ Qlo,
    const ushort_t* __restrict__ Khi, const ushort_t* __restrict__ Klo,
    const float* __restrict__ gb, float* __restrict__ out)
{
    __shared__ ushort_t elds[32 * 2048];    // 128 KiB
    __shared__ float lred[8][32];
    __shared__ float scv[32], gvv[32];
    const int t = threadIdx.x;
    const int lane = t & 63, w = t >> 6;
    const int l15 = lane & 15, l4 = lane >> 4;
    const int b  = blockIdx.x & 7;           // XCD-aligned batch
    const int i0 = (blockIdx.x >> 3) * 32;
    const size_t bN = (size_t)b * N;

    // Q fragments in registers (reused across the whole j-loop)
    bf16x8 qh_[2][4], ql_[2][4];
    #pragma unroll
    for (int rf = 0; rf < 2; ++rf) {
        const size_t ro = (bN + i0 + rf * 16 + l15) * A + l4 * 8;
        #pragma unroll
        for (int ks = 0; ks < 4; ++ks) {
            qh_[rf][ks] = *(const bf16x8*)(Qhi + ro + ks * 32);
            ql_[rf][ks] = *(const bf16x8*)(Qlo + ro + ks * 32);
        }
    }

    float lsum[8];
    #pragma unroll
    for (int u = 0; u < 8; ++u) lsum[u] = 0.f;

    for (int jt = 0; jt < 8; ++jt) {
        const int jb = jt * 256 + w * 32;
        bf16x8 bh_[2][4], bl_[2][4];
        #pragma unroll
        for (int cf = 0; cf < 2; ++cf) {
            const size_t co = (bN + jb + cf * 16 + l15) * A + l4 * 8;
            #pragma unroll
            for (int ks = 0; ks < 4; ++ks) {
                bh_[cf][ks] = *(const bf16x8*)(Khi + co + ks * 32);
                bl_[cf][ks] = *(const bf16x8*)(Klo + co + ks * 32);
            }
        }

        f32x4 acc[2][2];
        #pragma unroll
        for (int rf = 0; rf < 2; ++rf)
            #pragma unroll
            for (int cf = 0; cf < 2; ++cf) acc[rf][cf] = {0.f, 0.f, 0.f, 0.f};

        #pragma unroll
        for (int ks = 0; ks < 4; ++ks)
            #pragma unroll
            for (int rf = 0; rf < 2; ++rf)
                #pragma unroll
                for (int cf = 0; cf < 2; ++cf) {
                    acc[rf][cf] = mfma16(qh_[rf][ks], bh_[cf][ks], acc[rf][cf]);
                    acc[rf][cf] = mfma16(qh_[rf][ks], bl_[cf][ks], acc[rf][cf]);
                    acc[rf][cf] = mfma16(ql_[rf][ks], bh_[cf][ks], acc[rf][cf]);
                }

        #pragma unroll
        for (int rf = 0; rf < 2; ++rf)
            #pragma unroll
            for (int cf = 0; cf < 2; ++cf) {
                const int j = jb + cf * 16 + l15;
                #pragma unroll
                for (int g = 0; g < 4; ++g) {
                    const int ri = rf * 16 + l4 * 4 + g;
                    const float e = (i0 + ri == j) ? 0.f : __expf(acc[rf][cf][g]);
                    lsum[rf * 4 + g] += e;
                    elds[ri * 2048 + j] = f2bf(e);
                }
            }
    }

    // cross-lane + cross-wave row-sum reduction
    #pragma unroll
    for (int rf = 0; rf < 2; ++rf)
        #pragma unroll
        for (int g = 0; g < 4; ++g) {
            float v = lsum[rf * 4 + g];
            v += __shfl_xor(v, 1); v += __shfl_xor(v, 2);
            v += __shfl_xor(v, 4); v += __shfl_xor(v, 8);
            if (l15 == 0) lred[w][rf * 16 + l4 * 4 + g] = v;
        }
    __syncthreads();
    if (t < 32) {
        float l = 0.f;
        #pragma unroll
        for (int ww = 0; ww < 8; ++ww) l += lred[ww][t];
        const float gv = gb[bN + i0 + t];
        gvv[t] = gv;
        scv[t] = (1.f - gv) / l;
    }
    __syncthreads();

    // normalize + diagonal + coalesced f32 store
    #pragma unroll
    for (int it = 0; it < 16; ++it) {
        const int chunk = it * 512 + t;          // 0..8191
        const int ri = chunk >> 8;               // 32 rows
        const int c0 = (chunk & 255) * 8;
        const float sc = scv[ri], gv = gvv[ri];
        const int irow = i0 + ri;
        const uint4 ev = *(const uint4*)(elds + ri * 2048 + c0);
        float4 o0, o1;
        o0.x = (c0 + 0 == irow) ? gv : bf2f((ushort_t)(ev.x & 0xffffu)) * sc;
        o0.y = (c0 + 1 == irow) ? gv : bf2f((ushort_t)(ev.x >> 16)) * sc;
        o0.z = (c0 + 2 == irow) ? gv : bf2f((ushort_t)(ev.y & 0xffffu)) * sc;
        o0.w = (c0 + 3 == irow) ? gv : bf2f((ushort_t)(ev.y >> 16)) * sc;
        o1.x = (c0 + 4 == irow) ? gv : bf2f((ushort_t)(ev.z & 0xffffu)) * sc;
        o1.y = (c0 + 5 == irow) ? gv : bf2f((ushort_t)(ev.z >> 16)) * sc;
        o1.z = (c0 + 6 == irow) ? gv : bf2f((ushort_t)(ev.w & 0xffffu)) * sc;
        o1.w = (c0 + 7 == irow) ? gv : bf2f((ushort_t)(ev.w >> 16)) * sc;
        float* dst = out + (bN + irow) * N + c0;
        *(float4*)dst = o0;
        *(float4*)(dst + 4) = o1;
    }
}

extern "C" void kernel_launch(void* const* d_in, const int* in_sizes, int n_in,
                              void* d_out, int out_size, void* d_ws, size_t ws_size,
                              hipStream_t stream) {
    const float* x  = (const float*)d_in[0];
    const float* Wq = (const float*)d_in[1];
    const float* bq = (const float*)d_in[2];
    const float* Wk = (const float*)d_in[3];
    const float* bk = (const float*)d_in[4];
    const float* Wv = (const float*)d_in[5];
    const float* bv = (const float*)d_in[6];
    float* out = (float*)d_out;

    const size_t BNA = (size_t)B * N * A;
    ushort_t* Qhi = (ushort_t*)d_ws;                     // 4 MB each
    ushort_t* Qlo = Qhi + BNA;
    ushort_t* Khi = Qlo + BNA;
    ushort_t* Klo = Khi + BNA;
    ushort_t* WqTh = Klo + BNA;
    ushort_t* WqTl = WqTh + H * A;
    ushort_t* WkTh = WqTl + H * A;
    ushort_t* WkTl = WkTh + H * A;
    float* gb = (float*)(WkTl + H * A);                  // 64 KB

    k0_conv<<<(H * A) / 256, 256, 0, stream>>>(Wq, Wk, WqTh, WqTl, WkTh, WkTl);
    k1_mfma<<<(B * N) / 64, 256, 0, stream>>>(x, WqTh, WqTl, WkTh, WkTl,
                                              bq, bk, Wv, bv, Qhi, Qlo, Khi, Klo, gb);
    k2_fused<<<B * (N / 32), 512, 0, stream>>>(Qhi, Qlo, Khi, Klo, gb, out);
}